// Round 3
// baseline (940.981 us; speedup 1.0000x reference)
//
#include <hip/hip_runtime.h>

#define N_NODES 100000
#define N_EDGES 1600000
#define HIDDEN 64
#define NB 782      // ceil(N_NODES/128) buckets of 128 dst nodes
#define NSUB 8      // sub-lists per bucket (contention spreading)
#define CAP 512     // per-sub-list capacity; mean 256, sd 16 -> 16 sigma slack

// ---------------------------------------------------------------- K1: edge type, per-(dst,rel) counts, bucket append
// packed entry: bits[24:18]=d&127, bits[17:1]=src, bit0=t
__global__ void k_prep(const int* __restrict__ ei, const int* __restrict__ ntype,
                       int* __restrict__ cnt, int* __restrict__ bcnt,
                       unsigned int* __restrict__ tmp) {
    int e = blockIdx.x * 256 + threadIdx.x;
    if (e >= N_EDGES) return;
    int s = ei[e], d = ei[N_EDGES + e];
    int t = (ntype[s] == ntype[d]) ? 1 : 0;
    atomicAdd(&cnt[d * 2 + t], 1);
    int b = d >> 7;
    int sub = threadIdx.x & (NSUB - 1);
    int r = atomicAdd(&bcnt[b * NSUB + sub], 1);
    if (r < CAP)
        tmp[(b * NSUB + sub) * CAP + r] =
            ((unsigned)(d & 127) << 18) | ((unsigned)s << 1) | (unsigned)t;
}

// ---------------------------------------------------------------- K2: bucket-local layer-1 aggregation (LDS fp32 atomics)
__global__ __launch_bounds__(512) void k_agg1(const unsigned int* __restrict__ tmp,
                                              const int* __restrict__ bcnt,
                                              const int* __restrict__ cnt,
                                              const int* __restrict__ x,
                                              const float* __restrict__ emb,
                                              float* __restrict__ agg) {
    __shared__ float acc[128 * 128];  // 64 KB: [dlow][rel*64+ch]
    int b = blockIdx.x;
    int tid = threadIdx.x;
    for (int i = tid; i < 128 * 128; i += 512) acc[i] = 0.f;
    __syncthreads();

    int wave = tid >> 6, lane = tid & 63;  // 8 waves: wave w owns sub-list w
    int m = bcnt[b * NSUB + wave];
    if (m > CAP) m = CAP;
    const unsigned int* list = tmp + (b * NSUB + wave) * CAP;

    int base = 0;
    // main: full 64-entry batches
    for (; base + 64 <= m; base += 64) {
        unsigned entry = list[base + lane];
        int xs = x[(entry >> 1) & 0x1FFFF];
#pragma unroll 8
        for (int r = 0; r < 64; ++r) {
            unsigned pe = (unsigned)__builtin_amdgcn_readlane((int)entry, r);
            int xr = __builtin_amdgcn_readlane(xs, r);
            float v = emb[(long long)xr * HIDDEN + lane];
            int dlow = pe >> 18;
            int t = pe & 1;
            unsafeAtomicAdd(&acc[dlow * 128 + t * 64 + lane], v);
        }
    }
    // tail
    if (base < m) {
        int idx = base + lane;
        unsigned entry = 0u; int xs = 0;
        if (idx < m) { entry = list[idx]; xs = x[(entry >> 1) & 0x1FFFF]; }
        int nv = m - base;
        for (int r = 0; r < nv; ++r) {
            unsigned pe = (unsigned)__builtin_amdgcn_readlane((int)entry, r);
            int xr = __builtin_amdgcn_readlane(xs, r);
            float v = emb[(long long)xr * HIDDEN + lane];
            int dlow = pe >> 18;
            int t = pe & 1;
            unsafeAtomicAdd(&acc[dlow * 128 + t * 64 + lane], v);
        }
    }
    __syncthreads();

    // normalized dense write-out
    for (int k = tid; k < 128 * 128; k += 512) {
        int ni = k >> 7, c = k & 127;
        int node = b * 128 + ni;
        if (node < N_NODES) {
            int rel = c >> 6;
            int cc = cnt[node * 2 + rel];
            float norm = 1.f / (float)(cc > 1 ? cc : 1);
            agg[(long long)node * 128 + c] = acc[k] * norm;
        }
    }
}

// ---------------------------------------------------------------- K3: fused layer1 transform + relu + layer2 node scalars
// 256 threads = 4 waves; each wave handles 8 nodes; grid 3125 blocks
__global__ void k_layer1_fused(const int* __restrict__ x, const float* __restrict__ emb,
                               const float* __restrict__ agg,
                               const float* __restrict__ W1, const float* __restrict__ root1,
                               const float* __restrict__ b1,
                               const float* __restrict__ W2, const float* __restrict__ root2,
                               const float* __restrict__ b2,
                               float* __restrict__ s, float* __restrict__ out) {
    __shared__ float la[4][8][192];
    int w = threadIdx.x >> 6;
    int o = threadIdx.x & 63;
    int base = blockIdx.x * 32 + w * 8;

#pragma unroll
    for (int nb = 0; nb < 8; ++nb) {
        int node = base + nb;
        la[w][nb][o]       = agg[(long long)node * 128 + o];
        la[w][nb][64 + o]  = agg[(long long)node * 128 + 64 + o];
        la[w][nb][128 + o] = emb[(long long)x[node] * HIDDEN + o];
    }
    __syncthreads();

    float b1v = b1[o];
    float acc[8];
#pragma unroll
    for (int nb = 0; nb < 8; ++nb) acc[nb] = b1v;

#pragma unroll 4
    for (int h = 0; h < 64; ++h) {
        float w0 = W1[h * 64 + o];
        float w1 = W1[4096 + h * 64 + o];
        float wr = root1[h * 64 + o];
#pragma unroll
        for (int nb = 0; nb < 8; ++nb) {
            acc[nb] += la[w][nb][h] * w0;
            acc[nb] += la[w][nb][64 + h] * w1;
            acc[nb] += la[w][nb][128 + h] * wr;
        }
    }

    float w2a = W2[o], w2b = W2[64 + o], r2 = root2[o];
    float b2v = b2[0];
#pragma unroll
    for (int nb = 0; nb < 8; ++nb) {
        float h1v = acc[nb] > 0.f ? acc[nb] : 0.f;
        float p0 = h1v * w2a, p1 = h1v * w2b, p2 = h1v * r2;
        for (int off = 32; off >= 1; off >>= 1) {
            p0 += __shfl_down(p0, off);
            p1 += __shfl_down(p1, off);
            p2 += __shfl_down(p2, off);
        }
        if (o == 0) {
            int node = base + nb;
            s[node] = p0;
            s[N_NODES + node] = p1;
            out[node] = p2 + b2v;
        }
    }
}

// ---------------------------------------------------------------- K4: bucket-local layer-2 aggregation (scalar messages)
__global__ void k_gather2(const unsigned int* __restrict__ tmp, const int* __restrict__ bcnt,
                          const int* __restrict__ cnt, const float* __restrict__ sarr,
                          float* __restrict__ out) {
    __shared__ float acc2[256];  // [dlow][t]
    int b = blockIdx.x, tid = threadIdx.x;  // 256 threads
    acc2[tid] = 0.f;
    __syncthreads();
    for (int sub = 0; sub < NSUB; ++sub) {
        int m = bcnt[b * NSUB + sub];
        if (m > CAP) m = CAP;
        const unsigned int* list = tmp + (b * NSUB + sub) * CAP;
        for (int i = tid; i < m; i += 256) {
            unsigned pe = list[i];
            int t = pe & 1;
            int src = (pe >> 1) & 0x1FFFF;
            int dlow = pe >> 18;
            float sv = sarr[t * N_NODES + src];
            unsafeAtomicAdd(&acc2[dlow * 2 + t], sv);
        }
    }
    __syncthreads();
    if (tid < 128) {
        int node = b * 128 + tid;
        if (node < N_NODES) {
            int c0 = cnt[node * 2], c1 = cnt[node * 2 + 1];
            out[node] += acc2[tid * 2] / (float)(c0 > 1 ? c0 : 1)
                       + acc2[tid * 2 + 1] / (float)(c1 > 1 ? c1 : 1);
        }
    }
}

extern "C" void kernel_launch(void* const* d_in, const int* in_sizes, int n_in,
                              void* d_out, int out_size, void* d_ws, size_t ws_size,
                              hipStream_t stream) {
    const int* x      = (const int*)d_in[0];
    const int* ei     = (const int*)d_in[1];
    const int* ntype  = (const int*)d_in[2];
    const float* emb  = (const float*)d_in[3];
    const float* W1   = (const float*)d_in[4];
    const float* root1= (const float*)d_in[5];
    const float* b1   = (const float*)d_in[6];
    const float* W2   = (const float*)d_in[7];
    const float* root2= (const float*)d_in[8];
    const float* b2   = (const float*)d_in[9];
    float* out = (float*)d_out;

    char* ws = (char*)d_ws;
    size_t off = 0;
    auto alloc = [&](size_t bytes) -> void* {
        void* p = ws + off;
        off = (off + bytes + 255) & ~(size_t)255;
        return p;
    };
    int* cnt            = (int*)alloc((size_t)N_NODES * 2 * sizeof(int));
    int* bcnt           = (int*)alloc((size_t)NB * NSUB * sizeof(int));
    unsigned int* tmp   = (unsigned int*)alloc((size_t)NB * NSUB * CAP * sizeof(unsigned int));
    float* agg          = (float*)alloc((size_t)N_NODES * 2 * HIDDEN * sizeof(float));
    float* s            = (float*)alloc((size_t)N_NODES * 2 * sizeof(float));

    hipMemsetAsync(cnt, 0, (size_t)N_NODES * 2 * sizeof(int), stream);
    hipMemsetAsync(bcnt, 0, (size_t)NB * NSUB * sizeof(int), stream);

    k_prep<<<(N_EDGES + 255) / 256, 256, 0, stream>>>(ei, ntype, cnt, bcnt, tmp);
    k_agg1<<<NB, 512, 0, stream>>>(tmp, bcnt, cnt, x, emb, agg);
    k_layer1_fused<<<N_NODES / 32, 256, 0, stream>>>(x, emb, agg, W1, root1, b1,
                                                     W2, root2, b2, s, out);
    k_gather2<<<NB, 256, 0, stream>>>(tmp, bcnt, cnt, s, out);
}

// Round 4
// 622.928 us; speedup vs baseline: 1.5106x; 1.5106x over previous
//
#include <hip/hip_runtime.h>

#define N_NODES 100000
#define N_EDGES 1600000
#define HIDDEN 64
#define NBKT 196    // buckets of 512 dst nodes: 196*512 = 100352 >= N_NODES
#define NSUB 4      // sub-lists per bucket
#define CAP 2560    // per-sub-list capacity; mean ~2041, sd ~45 -> +11 sigma

// packed tmp entry: bits[26:18]=dlow(9b), bits[17:1]=src(17b), bit0=t
// ---------------------------------------------------------------- K1: bucket append
__global__ void k_prep(const int* __restrict__ ei, const int* __restrict__ ntype,
                       int* __restrict__ bcnt, unsigned int* __restrict__ tmp) {
    int e = blockIdx.x * 256 + threadIdx.x;
    if (e >= N_EDGES) return;
    int s = ei[e], d = ei[N_EDGES + e];
    int t = (ntype[s] == ntype[d]) ? 1 : 0;
    int b = d >> 9;
    int sub = threadIdx.x & (NSUB - 1);
    int r = atomicAdd(&bcnt[b * NSUB + sub], 1);
    if (r < CAP)
        tmp[(size_t)(b * NSUB + sub) * CAP + r] =
            ((unsigned)(d & 511) << 18) | ((unsigned)s << 1) | (unsigned)t;
}

// ---------------------------------------------------------------- K2: exclusive scan of bucket totals (1 block)
__global__ void k_bscan(const int* __restrict__ bcnt, int* __restrict__ bbase) {
    __shared__ int sc[256];
    int tid = threadIdx.x;
    int v = 0;
    if (tid < NBKT) {
        int tot = 0;
        for (int s = 0; s < NSUB; ++s) {
            int c = bcnt[tid * NSUB + s];
            tot += (c < CAP ? c : CAP);
        }
        v = tot;
    }
    sc[tid] = v;
    __syncthreads();
    for (int off = 1; off < 256; off <<= 1) {
        int a = sc[tid];
        int b = (tid >= off) ? sc[tid - off] : 0;
        __syncthreads();
        sc[tid] = a + b;
        __syncthreads();
    }
    if (tid < NBKT) bbase[tid] = sc[tid] - v;  // exclusive
}

// ---------------------------------------------------------------- K3: per-bucket counting sort -> csr, cnt, row_ptr
__global__ __launch_bounds__(512) void k_sort(const unsigned int* __restrict__ tmp,
                                              const int* __restrict__ bcnt,
                                              const int* __restrict__ bbase,
                                              int* __restrict__ cnt, int* __restrict__ row_ptr,
                                              int* __restrict__ csr) {
    __shared__ int hist[1024];   // [dlow*2 + t]
    __shared__ int psum[512];
    int b = blockIdx.x, tid = threadIdx.x;
    hist[tid] = 0; hist[512 + tid] = 0;
    __syncthreads();

    // pass 1: histogram
    for (int s = 0; s < NSUB; ++s) {
        int mm = bcnt[b * NSUB + s]; if (mm > CAP) mm = CAP;
        const unsigned int* list = tmp + (size_t)(b * NSUB + s) * CAP;
        for (int i = tid; i < mm; i += 512) {
            unsigned pe = list[i];
            atomicAdd(&hist[(pe >> 18) * 2 + (pe & 1)], 1);
        }
    }
    __syncthreads();

    // block scan over 1024 bins (pairwise: thread t owns bins 2t, 2t+1)
    int h0 = hist[2 * tid], h1 = hist[2 * tid + 1];
    psum[tid] = h0 + h1;
    __syncthreads();
    for (int off = 1; off < 512; off <<= 1) {
        int a = psum[tid];
        int b2 = (tid >= off) ? psum[tid - off] : 0;
        __syncthreads();
        psum[tid] = a + b2;
        __syncthreads();
    }
    int pairExcl = psum[tid] - (h0 + h1);
    __syncthreads();
    hist[2 * tid] = pairExcl;          // becomes running placement cursor
    hist[2 * tid + 1] = pairExcl + h0;

    int node = b * 512 + tid;
    if (node < N_NODES) {
        cnt[node * 2] = h0;
        cnt[node * 2 + 1] = h1;
        row_ptr[node] = bbase[b] + pairExcl;
    }
    __syncthreads();

    // pass 2: placement (csr stores bare src; rel implied by position)
    int base = bbase[b];
    for (int s = 0; s < NSUB; ++s) {
        int mm = bcnt[b * NSUB + s]; if (mm > CAP) mm = CAP;
        const unsigned int* list = tmp + (size_t)(b * NSUB + s) * CAP;
        for (int i = tid; i < mm; i += 512) {
            unsigned pe = list[i];
            int idx = (pe >> 18) * 2 + (pe & 1);
            int pos = base + atomicAdd(&hist[idx], 1);
            csr[pos] = (int)((pe >> 1) & 0x1FFFF);
        }
    }
}

// ---------------------------------------------------------------- K4: gather-aggregate layer 1 (wave per dst node)
__global__ void k_gather1(const int* __restrict__ csr, const int* __restrict__ row_ptr,
                          const int* __restrict__ cnt, const int* __restrict__ x,
                          const float* __restrict__ emb, float* __restrict__ agg) {
    int gid = blockIdx.x * blockDim.x + threadIdx.x;
    int n = gid >> 6;
    int lane = gid & 63;
    if (n >= N_NODES) return;
    int beg = row_ptr[n];
    int c0 = cnt[2 * n], c1 = cnt[2 * n + 1];
    int tot = c0 + c1;
    float a0 = 0.f, a1 = 0.f;
    int j = 0;
    for (; j + 4 <= tot; j += 4) {
        int s0 = csr[beg + j], s1 = csr[beg + j + 1], s2 = csr[beg + j + 2], s3 = csr[beg + j + 3];
        float v0 = emb[(long long)x[s0] * HIDDEN + lane];
        float v1 = emb[(long long)x[s1] * HIDDEN + lane];
        float v2 = emb[(long long)x[s2] * HIDDEN + lane];
        float v3 = emb[(long long)x[s3] * HIDDEN + lane];
        if (j + 0 < c0) a0 += v0; else a1 += v0;
        if (j + 1 < c0) a0 += v1; else a1 += v1;
        if (j + 2 < c0) a0 += v2; else a1 += v2;
        if (j + 3 < c0) a0 += v3; else a1 += v3;
    }
    for (; j < tot; ++j) {
        int s0 = csr[beg + j];
        float v = emb[(long long)x[s0] * HIDDEN + lane];
        if (j < c0) a0 += v; else a1 += v;
    }
    float n0 = 1.0f / (float)(c0 > 1 ? c0 : 1);
    float n1 = 1.0f / (float)(c1 > 1 ? c1 : 1);
    agg[(long long)n * 128 + lane] = a0 * n0;
    agg[(long long)n * 128 + 64 + lane] = a1 * n1;
}

// ---------------------------------------------------------------- K5: fused layer1 transform + relu + layer2 node scalars
__global__ void k_layer1_fused(const int* __restrict__ x, const float* __restrict__ emb,
                               const float* __restrict__ agg,
                               const float* __restrict__ W1, const float* __restrict__ root1,
                               const float* __restrict__ b1,
                               const float* __restrict__ W2, const float* __restrict__ root2,
                               const float* __restrict__ b2,
                               float* __restrict__ s, float* __restrict__ out) {
    __shared__ float la[4][8][192];
    int w = threadIdx.x >> 6;
    int o = threadIdx.x & 63;
    int base = blockIdx.x * 32 + w * 8;

#pragma unroll
    for (int nb = 0; nb < 8; ++nb) {
        int node = base + nb;
        la[w][nb][o]       = agg[(long long)node * 128 + o];
        la[w][nb][64 + o]  = agg[(long long)node * 128 + 64 + o];
        la[w][nb][128 + o] = emb[(long long)x[node] * HIDDEN + o];
    }
    __syncthreads();

    float b1v = b1[o];
    float acc[8];
#pragma unroll
    for (int nb = 0; nb < 8; ++nb) acc[nb] = b1v;

#pragma unroll 4
    for (int h = 0; h < 64; ++h) {
        float w0 = W1[h * 64 + o];
        float w1 = W1[4096 + h * 64 + o];
        float wr = root1[h * 64 + o];
#pragma unroll
        for (int nb = 0; nb < 8; ++nb) {
            acc[nb] += la[w][nb][h] * w0;
            acc[nb] += la[w][nb][64 + h] * w1;
            acc[nb] += la[w][nb][128 + h] * wr;
        }
    }

    float w2a = W2[o], w2b = W2[64 + o], r2 = root2[o];
    float b2v = b2[0];
#pragma unroll
    for (int nb = 0; nb < 8; ++nb) {
        float h1v = acc[nb] > 0.f ? acc[nb] : 0.f;
        float p0 = h1v * w2a, p1 = h1v * w2b, p2 = h1v * r2;
        for (int off = 32; off >= 1; off >>= 1) {
            p0 += __shfl_down(p0, off);
            p1 += __shfl_down(p1, off);
            p2 += __shfl_down(p2, off);
        }
        if (o == 0) {
            int node = base + nb;
            s[node] = p0;
            s[N_NODES + node] = p1;
            out[node] = p2 + b2v;
        }
    }
}

// ---------------------------------------------------------------- K6: layer-2 edge aggregation (wave per node, lanes over edges)
__global__ void k_gather2(const int* __restrict__ csr, const int* __restrict__ row_ptr,
                          const int* __restrict__ cnt, const float* __restrict__ sarr,
                          float* __restrict__ out) {
    int gid = blockIdx.x * blockDim.x + threadIdx.x;
    int n = gid >> 6;
    int lane = gid & 63;
    if (n >= N_NODES) return;
    int beg = row_ptr[n];
    int c0 = cnt[2 * n], c1 = cnt[2 * n + 1];
    int tot = c0 + c1;
    float n0 = 1.0f / (float)(c0 > 1 ? c0 : 1);
    float n1 = 1.0f / (float)(c1 > 1 ? c1 : 1);
    float acc = 0.f;
    for (int j = lane; j < tot; j += 64) {
        int src = csr[beg + j];
        acc += (j < c0) ? sarr[src] * n0 : sarr[N_NODES + src] * n1;
    }
    for (int off = 32; off >= 1; off >>= 1) acc += __shfl_down(acc, off);
    if (lane == 0) out[n] += acc;
}

extern "C" void kernel_launch(void* const* d_in, const int* in_sizes, int n_in,
                              void* d_out, int out_size, void* d_ws, size_t ws_size,
                              hipStream_t stream) {
    const int* x      = (const int*)d_in[0];
    const int* ei     = (const int*)d_in[1];
    const int* ntype  = (const int*)d_in[2];
    const float* emb  = (const float*)d_in[3];
    const float* W1   = (const float*)d_in[4];
    const float* root1= (const float*)d_in[5];
    const float* b1   = (const float*)d_in[6];
    const float* W2   = (const float*)d_in[7];
    const float* root2= (const float*)d_in[8];
    const float* b2   = (const float*)d_in[9];
    float* out = (float*)d_out;

    char* ws = (char*)d_ws;
    size_t off = 0;
    auto alloc = [&](size_t bytes) -> void* {
        void* p = ws + off;
        off = (off + bytes + 255) & ~(size_t)255;
        return p;
    };
    int* bcnt          = (int*)alloc((size_t)NBKT * NSUB * sizeof(int));
    int* bbase         = (int*)alloc((size_t)NBKT * sizeof(int));
    unsigned int* tmp  = (unsigned int*)alloc((size_t)NBKT * NSUB * CAP * sizeof(unsigned int));
    int* cnt           = (int*)alloc((size_t)N_NODES * 2 * sizeof(int));
    int* row_ptr       = (int*)alloc((size_t)N_NODES * sizeof(int));
    int* csr           = (int*)alloc((size_t)N_EDGES * sizeof(int));
    float* agg         = (float*)alloc((size_t)N_NODES * 2 * HIDDEN * sizeof(float));
    float* s           = (float*)alloc((size_t)N_NODES * 2 * sizeof(float));

    hipMemsetAsync(bcnt, 0, (size_t)NBKT * NSUB * sizeof(int), stream);

    k_prep<<<(N_EDGES + 255) / 256, 256, 0, stream>>>(ei, ntype, bcnt, tmp);
    k_bscan<<<1, 256, 0, stream>>>(bcnt, bbase);
    k_sort<<<NBKT, 512, 0, stream>>>(tmp, bcnt, bbase, cnt, row_ptr, csr);
    k_gather1<<<(N_NODES * 64) / 256, 256, 0, stream>>>(csr, row_ptr, cnt, x, emb, agg);
    k_layer1_fused<<<N_NODES / 32, 256, 0, stream>>>(x, emb, agg, W1, root1, b1,
                                                     W2, root2, b2, s, out);
    k_gather2<<<(N_NODES * 64) / 256, 256, 0, stream>>>(csr, row_ptr, cnt, s, out);
}